// Round 11
// baseline (462.584 us; speedup 1.0000x reference)
//
#include <hip/hip_runtime.h>
#include <math.h>

#define NN 50000
#define NE 800000
#define NPREB 2048   // k_pre grid (blocks); norm_part rows

typedef __attribute__((ext_vector_type(8))) short short8;
typedef __attribute__((ext_vector_type(4))) float floatx4;

__device__ __forceinline__ unsigned short bf16_of(float x) {
  unsigned u = __float_as_uint(x);
  u += 0x7fffu + ((u >> 16) & 1u);
  return (unsigned short)(u >> 16);
}
__device__ __forceinline__ float bf2f(unsigned short u) {
  return __uint_as_float(((unsigned)u) << 16);
}
__device__ __forceinline__ unsigned pack_bf(float a, float b) {
  unsigned ua = __float_as_uint(a); ua += 0x7fffu + ((ua >> 16) & 1u);
  unsigned ub = __float_as_uint(b); ub += 0x7fffu + ((ub >> 16) & 1u);
  return (ua >> 16) | (ub & 0xffff0000u);
}
__device__ __forceinline__ float blo(unsigned w) { return __uint_as_float(w << 16); }
__device__ __forceinline__ float bhi(unsigned w) { return __uint_as_float(w & 0xffff0000u); }

// ---------- k_pre: weights + q/hb GEMV + radial-norm partials + degree ------
// q/hb have NO dependency on deg/scan -> folded here from the old k_scanq
// (its 3125-block GEMV). One wave per node; Wq read direct fp32 (Wqp deleted
// -> no intra-kernel producer/consumer hazard). GEMV's dense FMA stream fills
// the latency bubbles of the random coord gathers in the edge loop.
__global__ __launch_bounds__(256)
void k_pre(const float* __restrict__ coord, const int* __restrict__ row,
           const int* __restrict__ col, const float* __restrict__ Wkv,
           const float* __restrict__ W1, const float* __restrict__ Wq,
           const float* __restrict__ bq, const float* __restrict__ h,
           float* __restrict__ norm_part, int* __restrict__ deg,
           unsigned short* __restrict__ Bkvb, unsigned short* __restrict__ W1tb,
           unsigned short* __restrict__ qg2, unsigned short* __restrict__ hb) {
  __shared__ float nred[4][16];
  __shared__ float sH[4][64];
  const int gid = blockIdx.x * 256 + threadIdx.x;
  const int np = gridDim.x * 256;
  for (int idx = gid; idx < 128 * 96; idx += np) {
    int n = idx & 127, kk = idx >> 7;
    float w = (n < 64) ? Wkv[kk * 128 + 2 * n] : Wkv[kk * 128 + 2 * (n - 64) + 1];
    Bkvb[n * 104 + kk] = bf16_of(w);
  }
  for (int idx = gid; idx < 64 * 64; idx += np) {
    int n = idx & 63, kk = idx >> 6;
    W1tb[n * 88 + kk] = bf16_of(W1[kk * 64 + n]);
  }
  const int lane = threadIdx.x & 63;
  const int wvb = threadIdx.x >> 6;
  const int wid = blockIdx.x * 4 + wvb;
  const int nw = gridDim.x * 4;
  // ---- q / hb: one wave per node, grid-stride ----
  for (int node = wid; node < NN; node += nw) {
    float hv = h[(size_t)node * 64 + lane];
    sH[wvb][lane] = hv;                      // same-wave write->read: lockstep
    hb[(size_t)node * 64 + lane] = bf16_of(hv);
    float q = bq[lane];
    const float* hr = sH[wvb];
#pragma unroll 8
    for (int i = 0; i < 64; ++i)
      q += hr[i] * Wq[i * 64 + lane];        // Wq 16KB, L1-hot, coalesced
    qg2[(size_t)node * 64 + (lane & 15) * 4 + (lane >> 4)] = bf16_of(q);
  }
  // ---- edge loop: radial-norm partials + degree ----
  const int grp = lane >> 4, g = lane & 15;
  const int c4 = g >> 2, f4 = g & 3;
  float acc = 0.f;
  for (int base = wid * 4; base < NE; base += nw * 4) {
    int e = base + grp;
    int r = row[e], c = col[e];
    float cd = 0.f;
    if (g < 12) cd = coord[r * 12 + g] - coord[c * 12 + g];
    float rad = 0.f;
#pragma unroll
    for (int d = 0; d < 3; ++d)
      rad += __shfl(cd, grp * 16 + c4 * 3 + d) * __shfl(cd, grp * 16 + f4 * 3 + d);
    acc += rad * rad;
    if (g == 0) atomicAdd(deg + r, 1);
  }
  acc += __shfl_xor(acc, 16);
  acc += __shfl_xor(acc, 32);
  if (lane < 16) nred[wvb][lane] = acc;
  __syncthreads();
  if (threadIdx.x < 16) {
    float s = nred[0][threadIdx.x] + nred[1][threadIdx.x] +
              nred[2][threadIdx.x] + nred[3][threadIdx.x];
    norm_part[blockIdx.x * 16 + threadIdx.x] = s;
  }
}

// ---------- k_scan: single block — norm reduce + CSR scan ----------
__global__ __launch_bounds__(1024)
void k_scan(const int* __restrict__ deg, int* __restrict__ cursor,
            const float* __restrict__ norm_part, float* __restrict__ rnorm) {
  __shared__ int part[1024];
  __shared__ float nr[64][16];
  const int t = threadIdx.x;
  {  // reduce norm_part[NPREB][16] -> rnorm[16]
    const int i = t >> 4, c = t & 15;
    float s = 0.f;
#pragma unroll
    for (int j = 0; j < NPREB / 64; ++j) s += norm_part[((i + 64 * j) << 4) + c];
    nr[i][c] = s;
  }
  __syncthreads();
  if (t < 16) {
    float s = 0.f;
#pragma unroll 8
    for (int i = 0; i < 64; ++i) s += nr[i][t];
    rnorm[t] = 1.0f / fmaxf(sqrtf(s), 1e-12f);
  }
  const int CH = (NN + 1023) / 1024;
  const int lo = t * CH, hi = (lo + CH < NN) ? lo + CH : NN;
  int s = 0;
  for (int i = lo; i < hi; ++i) s += deg[i];
  part[t] = s;
  __syncthreads();
  for (int off = 1; off < 1024; off <<= 1) {
    int v = (t >= off) ? part[t - off] : 0;
    __syncthreads();
    part[t] += v;
    __syncthreads();
  }
  int base = (t == 0) ? 0 : part[t - 1];
  for (int i = lo; i < hi; ++i) {
    cursor[i] = base; base += deg[i];
  }
}

// ---------- k_scatter: producer-side permute of edge data ----------
__global__ void k_scatter(const int* __restrict__ row, const int* __restrict__ col,
                          const float* __restrict__ edge_attr,
                          int* __restrict__ cursor, int* __restrict__ iperm,
                          unsigned* __restrict__ rcp, uint4* __restrict__ eab) {
  int e = blockIdx.x * 256 + threadIdx.x;
  if (e < NE) {
    int r = row[e], c = col[e];
    int p = atomicAdd(cursor + r, 1);
    iperm[e] = p;   // coalesced; lets k_fin write att coalesced
    rcp[p] = ((unsigned)r << 16) | (unsigned)c;
    const float4* ep = (const float4*)(edge_attr + (size_t)e * 16);
    float4 f0 = ep[0], f1 = ep[1], f2 = ep[2], f3 = ep[3];
    uint4 a, b;
    a.x = pack_bf(f0.x, f0.y); a.y = pack_bf(f0.z, f0.w);
    a.z = pack_bf(f1.x, f1.y); a.w = pack_bf(f1.z, f1.w);
    b.x = pack_bf(f2.x, f2.y); b.y = pack_bf(f2.z, f2.w);
    b.z = pack_bf(f3.x, f3.y); b.w = pack_bf(f3.z, f3.w);
    eab[(size_t)p * 2]     = a;
    eab[(size_t)p * 2 + 1] = b;
  }
}

// -------- main fused kernel (frozen — k_kv deltas < noise band) ------
__global__ __launch_bounds__(512, 6)
void k_kv(const unsigned short* __restrict__ hb, const float* __restrict__ coord,
          const float* __restrict__ bkv, const float* __restrict__ b1,
          const float* __restrict__ W2, const float* __restrict__ rnorm,
          const unsigned* __restrict__ rcp, const uint4* __restrict__ eab,
          const unsigned short* __restrict__ Bkvb,
          const unsigned short* __restrict__ W1tb,
          const unsigned short* __restrict__ qg2,
          float* __restrict__ exg, float* __restrict__ l_g,
          float* __restrict__ hacc_g, float* __restrict__ cacc_g) {
  __shared__ __align__(16) unsigned short sA[128][104];   // feat bf16; later v + cd
  __shared__ __align__(16) unsigned short sB[128][104];   // [k|v]^T bf16; later W1^T
  __shared__ unsigned sRC[128];                           // row<<16 | col
  unsigned short (*sW1t)[88] = (unsigned short (*)[88])&sB[0][0];

  const int tid = threadIdx.x;
  const int base = blockIdx.x * 128;

  // prefetch W1^T (11,264 B) into registers; parked into sB's space post-GEMM1
  const uint4* gw = (const uint4*)W1tb;
  uint4 w1a = gw[tid];                 // 704 uint4 total; tid<512 all valid
  uint4 w1b;
  if (tid < 192) w1b = gw[512 + tid];

  if (tid < 128) sRC[tid] = rcp[base + tid];        // for post-GEMM phases
  if (tid < 256) {                                  // edge_attr bf16, coalesced
    int s = tid >> 1;
    *(uint4*)&sA[s][80 + (tid & 1) * 8] = eab[(size_t)base * 2 + tid];
  }
  // hb gather starts immediately — col from rcp directly (8-way uniform)
  for (int idx = tid; idx < 1024; idx += 512) {
    int s = idx >> 3, k8 = idx & 7;
    unsigned c = rcp[base + s] & 0xffffu;
    uint4 u = ((const uint4*)(hb + (size_t)c * 64))[k8];
    *(uint4*)&sA[s][16 + k8 * 8] = u;
  }
  {
    const uint4* gb = (const uint4*)Bkvb;
    uint4* sb = (uint4*)&sB[0][0];
    for (int idx = tid; idx < 1664; idx += 512) sb[idx] = gb[idx];
  }
  const int wv = tid >> 6, lane = tid & 63;
  float cdp[4];   // this wave's coord_diff values, parked to LDS after GEMM1
  {
    const int grp = lane >> 4, g = lane & 15;
    const int c4 = g >> 2, f4 = g & 3;
    const float rn = rnorm[g];
#pragma unroll
    for (int it = 0; it < 4; ++it) {
      int slot = 16 * wv + it * 4 + grp;
      unsigned rc = rcp[base + slot];               // uniform per 16-lane group
      int r = (int)(rc >> 16), c = (int)(rc & 0xffffu);
      float cd = 0.f;
      if (g < 12) cd = coord[r * 12 + g] - coord[c * 12 + g];
      cdp[it] = cd;
      float rad = 0.f;
#pragma unroll
      for (int d = 0; d < 3; ++d)
        rad += __shfl(cd, grp * 16 + c4 * 3 + d) * __shfl(cd, grp * 16 + f4 * 3 + d);
      sA[slot][g] = bf16_of(rad * rn);
    }
  }
  __syncthreads();   // single staging barrier: sA + sB + sRC all visible

  const int m16 = lane & 15, quad = lane >> 4;
  const int arow = 16 * wv + m16;

  // kv = feat @ [Wk|Wv]
  floatx4 acc[8];
#pragma unroll
  for (int i = 0; i < 8; ++i) acc[i] = (floatx4){0.f, 0.f, 0.f, 0.f};
#pragma unroll
  for (int ks = 0; ks < 3; ++ks) {
    short8 af = *(const short8*)&sA[arow][ks * 32 + quad * 8];
#pragma unroll
    for (int nt = 0; nt < 8; ++nt) {
      short8 bf = *(const short8*)&sB[nt * 16 + m16][ks * 32 + quad * 8];
      acc[nt] = __builtin_amdgcn_mfma_f32_16x16x32_bf16(af, bf, acc[nt], 0, 0, 0);
    }
  }
#pragma unroll
  for (int nt = 0; nt < 4; ++nt) {
    float bk = bkv[2 * (m16 + 16 * nt)];
    float bv = bkv[2 * (m16 + 16 * nt) + 1];
#pragma unroll
    for (int r = 0; r < 4; ++r) { acc[nt][r] += bk; acc[nt + 4][r] += bv; }
  }
  // alpha = q . k -> ex = exp(alpha)   (no max stabilizer: |alpha| << 88)
  float part[4] = {0.f, 0.f, 0.f, 0.f};
#pragma unroll
  for (int r = 0; r < 4; ++r) {
    unsigned nrow = sRC[16 * wv + quad * 4 + r] >> 16;
    uint2 qp = *(const uint2*)(qg2 + (size_t)nrow * 64 + m16 * 4);
    part[r] += blo(qp.x) * acc[0][r] + bhi(qp.x) * acc[1][r] +
               blo(qp.y) * acc[2][r] + bhi(qp.y) * acc[3][r];
  }
#pragma unroll
  for (int off = 1; off < 16; off <<= 1) {
#pragma unroll
    for (int r = 0; r < 4; ++r) part[r] += __shfl_xor(part[r], off);
  }
  float ex[4];
#pragma unroll
  for (int r = 0; r < 4; ++r) ex[r] = __expf(part[r]);
  if (m16 == 0) {
#pragma unroll
    for (int r = 0; r < 4; ++r)
      exg[base + 16 * wv + quad * 4 + r] = ex[r];
  }
  // v (bf16) -> sA rows (wave-private) for the W1 GEMM; keep fp32 v in acc[4..7]
#pragma unroll
  for (int nt = 0; nt < 4; ++nt)
#pragma unroll
    for (int r = 0; r < 4; ++r)
      sA[16 * wv + quad * 4 + r][m16 + 16 * nt] = bf16_of(acc[4 + nt][r]);
  // park coord_diff in sA cols 64..75 (dead after this wave's own A-reads)
#pragma unroll
  for (int it = 0; it < 4; ++it)
    if (m16 < 12) sA[16 * wv + it * 4 + quad][64 + m16] = bf16_of(cdp[it]);

  __syncthreads();   // all waves done reading sB (GEMM1)
  {                  // overlay W1^T into sB's space from prefetched regs
    unsigned short* sw = &sB[0][0];
    *(uint4*)&sw[(size_t)tid * 8] = w1a;
    if (tid < 192) *(uint4*)&sw[(size_t)(512 + tid) * 8] = w1b;
  }
  __syncthreads();   // sW1t visible

  // t = silu(v @ W1 + b1)
  floatx4 tacc[4];
#pragma unroll
  for (int i = 0; i < 4; ++i) tacc[i] = (floatx4){0.f, 0.f, 0.f, 0.f};
#pragma unroll
  for (int ks = 0; ks < 2; ++ks) {
    short8 af = *(const short8*)&sA[arow][ks * 32 + quad * 8];
#pragma unroll
    for (int nt = 0; nt < 4; ++nt) {
      short8 bf = *(const short8*)&sW1t[nt * 16 + m16][ks * 32 + quad * 8];
      tacc[nt] = __builtin_amdgcn_mfma_f32_16x16x32_bf16(af, bf, tacc[nt], 0, 0, 0);
    }
  }
#pragma unroll
  for (int nt = 0; nt < 4; ++nt) {
    float bb = b1[m16 + 16 * nt];
#pragma unroll
    for (int r = 0; r < 4; ++r) {
      float t = tacc[nt][r] + bb;
      tacc[nt][r] = t * __builtin_amdgcn_rcpf(1.f + __expf(-t));  // silu, rcp
    }
  }
  // cv = t @ W2 : local partials, then 16-lane REDUCE-SCATTER (15 shfl)
  float w0[16];   // j = r*4+c
#pragma unroll
  for (int r = 0; r < 4; ++r)
#pragma unroll
    for (int c = 0; c < 4; ++c) w0[r * 4 + c] = 0.f;
#pragma unroll
  for (int nt = 0; nt < 4; ++nt) {
    float4 w2r = ((const float4*)W2)[m16 + 16 * nt];
#pragma unroll
    for (int r = 0; r < 4; ++r) {
      w0[r * 4 + 0] += tacc[nt][r] * w2r.x;
      w0[r * 4 + 1] += tacc[nt][r] * w2r.y;
      w0[r * 4 + 2] += tacc[nt][r] * w2r.z;
      w0[r * 4 + 3] += tacc[nt][r] * w2r.w;
    }
  }
  float rs1[8];
#pragma unroll
  for (int jj = 0; jj < 8; ++jj) {
    float snd = (m16 & 8) ? w0[jj] : w0[jj + 8];
    float rcv = __shfl_xor(snd, 8);
    rs1[jj] = ((m16 & 8) ? w0[jj + 8] : w0[jj]) + rcv;
  }
  float rs2[4];
#pragma unroll
  for (int jj = 0; jj < 4; ++jj) {
    float snd = (m16 & 4) ? rs1[jj] : rs1[jj + 4];
    float rcv = __shfl_xor(snd, 4);
    rs2[jj] = ((m16 & 4) ? rs1[jj + 4] : rs1[jj]) + rcv;
  }
  float rs3[2];
#pragma unroll
  for (int jj = 0; jj < 2; ++jj) {
    float snd = (m16 & 2) ? rs2[jj] : rs2[jj + 2];
    float rcv = __shfl_xor(snd, 2);
    rs3[jj] = ((m16 & 2) ? rs2[jj + 2] : rs2[jj]) + rcv;
  }
  float cvtot;
  {
    float snd = (m16 & 1) ? rs3[0] : rs3[1];
    float rcv = __shfl_xor(snd, 1);
    cvtot = ((m16 & 1) ? rs3[1] : rs3[0]) + rcv;
  }
  // lane m16 holds cv[r=m16>>2][c=m16&3]; lane d wants channel d/3
  const int d3 = (m16 < 12) ? ((m16 * 11) >> 5) : 3;
  float tr[4];
#pragma unroll
  for (int r = 0; r < 4; ++r) {
    float cvv = __shfl(cvtot, (quad << 4) + r * 4 + d3);
    tr[r] = (m16 < 12) ? bf2f(sA[16 * wv + quad * 4 + r][64 + m16]) * cvv : 0.f;
  }

  // ---- per-wave segment reduce over this wave's 16 slots + atomics ----
  int s = 0;
  while (s < 16) {
    int n = (int)(sRC[16 * wv + s] >> 16);        // uniform (broadcast)
    int e2 = s + 1;
    while (e2 < 16 && (int)(sRC[16 * wv + e2] >> 16) == n) ++e2;
    float hp0 = 0.f, hp1 = 0.f, hp2 = 0.f, hp3 = 0.f, lp = 0.f, cp = 0.f;
#pragma unroll
    for (int r = 0; r < 4; ++r) {
      int rowi = quad * 4 + r;
      float w = (rowi >= s && rowi < e2) ? ex[r] : 0.f;
      hp0 += w * acc[4][r];
      hp1 += w * acc[5][r];
      hp2 += w * acc[6][r];
      hp3 += w * acc[7][r];
      lp  += (rowi >= s && rowi < e2) ? ex[r] : 0.f;
      cp  += w * tr[r];
    }
    hp0 += __shfl_xor(hp0, 16); hp0 += __shfl_xor(hp0, 32);
    hp1 += __shfl_xor(hp1, 16); hp1 += __shfl_xor(hp1, 32);
    hp2 += __shfl_xor(hp2, 16); hp2 += __shfl_xor(hp2, 32);
    hp3 += __shfl_xor(hp3, 16); hp3 += __shfl_xor(hp3, 32);
    lp  += __shfl_xor(lp, 16);  lp  += __shfl_xor(lp, 32);
    cp  += __shfl_xor(cp, 16);  cp  += __shfl_xor(cp, 32);
    if (quad == 0) {
      float* hg = hacc_g + (size_t)n * 64;
      atomicAdd(hg + m16,      hp0);
      atomicAdd(hg + m16 + 16, hp1);
      atomicAdd(hg + m16 + 32, hp2);
      atomicAdd(hg + m16 + 48, hp3);
      if (m16 < 12) atomicAdd(cacc_g + (size_t)n * 12 + m16, cp);
      if (m16 == 0) atomicAdd(l_g + n, lp);
    }
    s = e2;
  }
}

// ---------------- finalize (float4-granular: 16 threads/node) ----------------
__global__ __launch_bounds__(256)
void k_fin(const float* __restrict__ h, const float* __restrict__ coord,
           const int* __restrict__ row, const int* __restrict__ iperm,
           const float* __restrict__ exg, const float* __restrict__ l_g,
           const float* __restrict__ hacc_g, const float* __restrict__ cacc_g,
           float* __restrict__ out) {
  const int node = blockIdx.x * 16 + (threadIdx.x >> 4);
  const int q16 = threadIdx.x & 15;
  const float l = l_g[node];
  const float inv = (l > 0.f) ? 1.f / l : 0.f;
  {
    float4 hv = ((const float4*)(h + (size_t)node * 64))[q16];
    float4 av = ((const float4*)(hacc_g + (size_t)node * 64))[q16];
    float4 o;
    o.x = hv.x + av.x * inv; o.y = hv.y + av.y * inv;
    o.z = hv.z + av.z * inv; o.w = hv.w + av.w * inv;
    ((float4*)(out + (size_t)node * 64))[q16] = o;
  }
  if (q16 < 3) {
    float4 cv = ((const float4*)(coord + (size_t)node * 12))[q16];
    float4 av = ((const float4*)(cacc_g + (size_t)node * 12))[q16];
    float4 o;
    o.x = cv.x + av.x * inv; o.y = cv.y + av.y * inv;
    o.z = cv.z + av.z * inv; o.w = cv.w + av.w * inv;
    ((float4*)(out + (size_t)NN * 64 + (size_t)node * 12))[q16] = o;
  }
  const int e = blockIdx.x * 256 + threadIdx.x;   // covers [0, NE) exactly
  float le = l_g[row[e]];                          // node with an edge: le > 0
  out[(size_t)NN * 64 + NN * 12 + e] = exg[iperm[e]] * __builtin_amdgcn_rcpf(le);
}

extern "C" void kernel_launch(void* const* d_in, const int* in_sizes, int n_in,
                              void* d_out, int out_size, void* d_ws, size_t ws_size,
                              hipStream_t stream) {
  const float* h         = (const float*)d_in[0];
  const float* coord     = (const float*)d_in[1];
  const int*   row       = (const int*)d_in[2];
  const int*   col       = (const int*)d_in[3];
  const float* edge_attr = (const float*)d_in[4];
  const float* Wq        = (const float*)d_in[5];
  const float* bq        = (const float*)d_in[6];
  const float* Wkv       = (const float*)d_in[7];
  const float* bkv       = (const float*)d_in[8];
  const float* W1        = (const float*)d_in[9];
  const float* b1        = (const float*)d_in[10];
  const float* W2        = (const float*)d_in[11];
  float* out = (float*)d_out;

  size_t off = 0;
  char* wsb = (char*)d_ws;
  auto alloc = [&](size_t bytes) {
    off = (off + 255) & ~(size_t)255;
    void* p = wsb + off; off += bytes; return p;
  };
  // ---- zeroed region (contiguous, one memset) ----
  int*            deg      = (int*)alloc((size_t)NN * 4);
  float*          l_g      = (float*)alloc((size_t)NN * 4);
  float*          hacc_g   = (float*)alloc((size_t)NN * 64 * 4);
  float*          cacc_g   = (float*)alloc((size_t)NN * 12 * 4);
  size_t zbytes = off;
  // ---- rest ----
  float*          norm_part= (float*)alloc((size_t)NPREB * 16 * 4);
  float*          rnorm    = (float*)alloc(16 * 4);
  int*            cursor   = (int*)alloc((size_t)NN * 4);
  unsigned*       rcp      = (unsigned*)alloc((size_t)NE * 4);
  int*            iperm    = (int*)alloc((size_t)NE * 4);
  float*          exg      = (float*)alloc((size_t)NE * 4);
  uint4*          eab      = (uint4*)alloc((size_t)NE * 32);
  unsigned short* qg2      = (unsigned short*)alloc((size_t)NN * 64 * 2);
  unsigned short* hb       = (unsigned short*)alloc((size_t)NN * 64 * 2);
  unsigned short* Bkvb     = (unsigned short*)alloc(128 * 104 * 2);
  unsigned short* W1tb     = (unsigned short*)alloc(64 * 88 * 2);

  hipMemsetAsync(d_ws, 0, zbytes, stream);

  k_pre<<<NPREB, 256, 0, stream>>>(coord, row, col, Wkv, W1, Wq, bq, h,
                                   norm_part, deg, Bkvb, W1tb, qg2, hb);
  k_scan<<<1, 1024, 0, stream>>>(deg, cursor, norm_part, rnorm);
  k_scatter<<<(NE + 255) / 256, 256, 0, stream>>>(row, col, edge_attr, cursor,
                                                  iperm, rcp, eab);
  k_kv<<<NE / 128, 512, 0, stream>>>(hb, coord, bkv, b1, W2, rnorm,
                                     rcp, eab, Bkvb, W1tb, qg2,
                                     exg, l_g, hacc_g, cacc_g);
  k_fin<<<NN / 16, 256, 0, stream>>>(h, coord, row, iperm, exg, l_g,
                                     hacc_g, cacc_g, out);
}

// Round 12
// 430.588 us; speedup vs baseline: 1.0743x; 1.0743x over previous
//
#include <hip/hip_runtime.h>
#include <math.h>

#define NN 50000
#define NE 800000
#define NPREB 1024   // k_pre grid (blocks); norm_part rows

typedef __attribute__((ext_vector_type(8))) short short8;
typedef __attribute__((ext_vector_type(4))) float floatx4;

__device__ __forceinline__ unsigned short bf16_of(float x) {
  unsigned u = __float_as_uint(x);
  u += 0x7fffu + ((u >> 16) & 1u);
  return (unsigned short)(u >> 16);
}
__device__ __forceinline__ float bf2f(unsigned short u) {
  return __uint_as_float(((unsigned)u) << 16);
}
__device__ __forceinline__ unsigned pack_bf(float a, float b) {
  unsigned ua = __float_as_uint(a); ua += 0x7fffu + ((ua >> 16) & 1u);
  unsigned ub = __float_as_uint(b); ub += 0x7fffu + ((ub >> 16) & 1u);
  return (ua >> 16) | (ub & 0xffff0000u);
}
__device__ __forceinline__ float blo(unsigned w) { return __uint_as_float(w << 16); }
__device__ __forceinline__ float bhi(unsigned w) { return __uint_as_float(w & 0xffff0000u); }

// ---------- k_pre: weight conversion + radial-norm partials + degree count ----------
// Edge loop rewritten PER-THREAD: 6 float4 loads/edge (was 24 scalar gathers
// spread over 16 lanes), einsum fully in-register (was 6 shfl/lane/edge),
// wave-reduce ONCE at the end (96 shfl) instead of per-edge.
__global__ __launch_bounds__(256)
void k_pre(const float* __restrict__ coord, const int* __restrict__ row,
           const int* __restrict__ col, const float* __restrict__ Wkv,
           const float* __restrict__ W1, const float* __restrict__ Wq,
           float* __restrict__ norm_part, int* __restrict__ deg,
           unsigned short* __restrict__ Bkvb, unsigned short* __restrict__ W1tb,
           unsigned* __restrict__ Wqp) {
  __shared__ float nred[4][16];
  const int gid = blockIdx.x * 256 + threadIdx.x;
  const int np = gridDim.x * 256;
  for (int idx = gid; idx < 128 * 96; idx += np) {
    int n = idx & 127, kk = idx >> 7;
    float w = (n < 64) ? Wkv[kk * 128 + 2 * n] : Wkv[kk * 128 + 2 * (n - 64) + 1];
    Bkvb[n * 104 + kk] = bf16_of(w);
  }
  for (int idx = gid; idx < 64 * 64; idx += np) {
    int n = idx & 63, kk = idx >> 6;
    W1tb[n * 88 + kk] = bf16_of(W1[kk * 64 + n]);
  }
  for (int idx = gid; idx < 32 * 64; idx += np) {
    int i2 = idx >> 6, j = idx & 63;
    Wqp[idx] = pack_bf(Wq[(2 * i2) * 64 + j], Wq[(2 * i2 + 1) * 64 + j]);
  }
  // ---- per-thread edge loop ----
  float accv[16];
#pragma unroll
  for (int j = 0; j < 16; ++j) accv[j] = 0.f;
  for (int e = gid; e < NE; e += np) {
    int r = row[e], c = col[e];
    const float4* cr = (const float4*)(coord + (size_t)r * 12);
    const float4* cc = (const float4*)(coord + (size_t)c * 12);
    float cd[12];
#pragma unroll
    for (int q = 0; q < 3; ++q) {
      float4 a = cr[q], b = cc[q];
      cd[q * 4 + 0] = a.x - b.x; cd[q * 4 + 1] = a.y - b.y;
      cd[q * 4 + 2] = a.z - b.z; cd[q * 4 + 3] = a.w - b.w;
    }
#pragma unroll
    for (int c4 = 0; c4 < 4; ++c4)
#pragma unroll
      for (int f4 = 0; f4 < 4; ++f4) {
        float v = cd[c4 * 3] * cd[f4 * 3] + cd[c4 * 3 + 1] * cd[f4 * 3 + 1] +
                  cd[c4 * 3 + 2] * cd[f4 * 3 + 2];
        accv[c4 * 4 + f4] += v * v;
      }
    atomicAdd(deg + r, 1);
  }
  // ---- one-time wave butterfly + block reduce ----
  const int lane = threadIdx.x & 63, wvb = threadIdx.x >> 6;
#pragma unroll
  for (int j = 0; j < 16; ++j) {
    accv[j] += __shfl_xor(accv[j], 1);
    accv[j] += __shfl_xor(accv[j], 2);
    accv[j] += __shfl_xor(accv[j], 4);
    accv[j] += __shfl_xor(accv[j], 8);
    accv[j] += __shfl_xor(accv[j], 16);
    accv[j] += __shfl_xor(accv[j], 32);
  }
  if (lane == 0) {
#pragma unroll
    for (int j = 0; j < 16; ++j) nred[wvb][j] = accv[j];   // static indices
  }
  __syncthreads();
  if (threadIdx.x < 16) {
    float s = nred[0][threadIdx.x] + nred[1][threadIdx.x] +
              nred[2][threadIdx.x] + nred[3][threadIdx.x];
    norm_part[blockIdx.x * 16 + threadIdx.x] = s;
  }
}

// ---------- k_scanq: block 0 = norm reduce + CSR scan; blocks >=1 = q/hb ----------
__global__ __launch_bounds__(1024)
void k_scanq(const int* __restrict__ deg, int* __restrict__ cursor,
             const float* __restrict__ norm_part, float* __restrict__ rnorm,
             const float* __restrict__ h, const unsigned* __restrict__ Wqp,
             const float* __restrict__ bq,
             unsigned short* __restrict__ qg2, unsigned short* __restrict__ hb) {
  __shared__ int part[1024];
  __shared__ float nr[64][16];
  __shared__ float sHr[16][64];
  const int t = threadIdx.x;
  if (blockIdx.x == 0) {
    {  // reduce norm_part[NPREB][16] -> rnorm[16], no atomics
      const int i = t >> 4, c = t & 15;
      float s = 0.f;
#pragma unroll
      for (int j = 0; j < NPREB / 64; ++j) s += norm_part[((i + 64 * j) << 4) + c];
      nr[i][c] = s;
    }
    __syncthreads();
    if (t < 16) {
      float s = 0.f;
#pragma unroll 8
      for (int i = 0; i < 64; ++i) s += nr[i][t];
      rnorm[t] = 1.0f / fmaxf(sqrtf(s), 1e-12f);
    }
    const int CH = (NN + 1023) / 1024;
    const int lo = t * CH, hi = (lo + CH < NN) ? lo + CH : NN;
    int s = 0;
    for (int i = lo; i < hi; ++i) s += deg[i];
    part[t] = s;
    __syncthreads();
    for (int off = 1; off < 1024; off <<= 1) {
      int v = (t >= off) ? part[t - off] : 0;
      __syncthreads();
      part[t] += v;
      __syncthreads();
    }
    int base = (t == 0) ? 0 : part[t - 1];
    for (int i = lo; i < hi; ++i) {
      cursor[i] = base; base += deg[i];
    }
    return;
  }
  const int wv = t >> 6, lane = t & 63;
  const int node = (blockIdx.x - 1) * 16 + wv;
  float hv = h[(size_t)node * 64 + lane];
  sHr[wv][lane] = hv;   // same-wave write->read: lockstep, no barrier needed
  hb[(size_t)node * 64 + lane] = bf16_of(hv);
  float q = bq[lane];
  const float2* hp = (const float2*)sHr[wv];
#pragma unroll 8
  for (int i2 = 0; i2 < 32; ++i2) {
    unsigned w = Wqp[i2 * 64 + lane];   // global, L1-hot, coalesced
    float2 hbv = hp[i2];
    q += hbv.x * blo(w) + hbv.y * bhi(w);
  }
  qg2[(size_t)node * 64 + (lane & 15) * 4 + (lane >> 4)] = bf16_of(q);
}

// ---------- k_scatter: producer-side permute of edge data ----------
__global__ void k_scatter(const int* __restrict__ row, const int* __restrict__ col,
                          const float* __restrict__ edge_attr,
                          int* __restrict__ cursor, int* __restrict__ iperm,
                          unsigned* __restrict__ rcp, uint4* __restrict__ eab) {
  int e = blockIdx.x * 256 + threadIdx.x;
  if (e < NE) {
    int r = row[e], c = col[e];
    int p = atomicAdd(cursor + r, 1);
    iperm[e] = p;   // coalesced; lets k_fin write att coalesced
    rcp[p] = ((unsigned)r << 16) | (unsigned)c;
    const float4* ep = (const float4*)(edge_attr + (size_t)e * 16);
    float4 f0 = ep[0], f1 = ep[1], f2 = ep[2], f3 = ep[3];
    uint4 a, b;
    a.x = pack_bf(f0.x, f0.y); a.y = pack_bf(f0.z, f0.w);
    a.z = pack_bf(f1.x, f1.y); a.w = pack_bf(f1.z, f1.w);
    b.x = pack_bf(f2.x, f2.y); b.y = pack_bf(f2.z, f2.w);
    b.z = pack_bf(f3.x, f3.y); b.w = pack_bf(f3.z, f3.w);
    eab[(size_t)p * 2]     = a;
    eab[(size_t)p * 2 + 1] = b;
  }
}

// -------- main fused kernel (frozen — k_kv deltas < noise band) ------
__global__ __launch_bounds__(512, 6)
void k_kv(const unsigned short* __restrict__ hb, const float* __restrict__ coord,
          const float* __restrict__ bkv, const float* __restrict__ b1,
          const float* __restrict__ W2, const float* __restrict__ rnorm,
          const unsigned* __restrict__ rcp, const uint4* __restrict__ eab,
          const unsigned short* __restrict__ Bkvb,
          const unsigned short* __restrict__ W1tb,
          const unsigned short* __restrict__ qg2,
          float* __restrict__ exg, float* __restrict__ l_g,
          float* __restrict__ hacc_g, float* __restrict__ cacc_g) {
  __shared__ __align__(16) unsigned short sA[128][104];   // feat bf16; later v + cd
  __shared__ __align__(16) unsigned short sB[128][104];   // [k|v]^T bf16; later W1^T
  __shared__ unsigned sRC[128];                           // row<<16 | col
  unsigned short (*sW1t)[88] = (unsigned short (*)[88])&sB[0][0];

  const int tid = threadIdx.x;
  const int base = blockIdx.x * 128;

  // prefetch W1^T (11,264 B) into registers; parked into sB's space post-GEMM1
  const uint4* gw = (const uint4*)W1tb;
  uint4 w1a = gw[tid];                 // 704 uint4 total; tid<512 all valid
  uint4 w1b;
  if (tid < 192) w1b = gw[512 + tid];

  if (tid < 128) sRC[tid] = rcp[base + tid];        // for post-GEMM phases
  if (tid < 256) {                                  // edge_attr bf16, coalesced
    int s = tid >> 1;
    *(uint4*)&sA[s][80 + (tid & 1) * 8] = eab[(size_t)base * 2 + tid];
  }
  // hb gather starts immediately — col from rcp directly (8-way uniform)
  for (int idx = tid; idx < 1024; idx += 512) {
    int s = idx >> 3, k8 = idx & 7;
    unsigned c = rcp[base + s] & 0xffffu;
    uint4 u = ((const uint4*)(hb + (size_t)c * 64))[k8];
    *(uint4*)&sA[s][16 + k8 * 8] = u;
  }
  {
    const uint4* gb = (const uint4*)Bkvb;
    uint4* sb = (uint4*)&sB[0][0];
    for (int idx = tid; idx < 1664; idx += 512) sb[idx] = gb[idx];
  }
  const int wv = tid >> 6, lane = tid & 63;
  float cdp[4];   // this wave's coord_diff values, parked to LDS after GEMM1
  {
    const int grp = lane >> 4, g = lane & 15;
    const int c4 = g >> 2, f4 = g & 3;
    const float rn = rnorm[g];
#pragma unroll
    for (int it = 0; it < 4; ++it) {
      int slot = 16 * wv + it * 4 + grp;
      unsigned rc = rcp[base + slot];               // uniform per 16-lane group
      int r = (int)(rc >> 16), c = (int)(rc & 0xffffu);
      float cd = 0.f;
      if (g < 12) cd = coord[r * 12 + g] - coord[c * 12 + g];
      cdp[it] = cd;
      float rad = 0.f;
#pragma unroll
      for (int d = 0; d < 3; ++d)
        rad += __shfl(cd, grp * 16 + c4 * 3 + d) * __shfl(cd, grp * 16 + f4 * 3 + d);
      sA[slot][g] = bf16_of(rad * rn);
    }
  }
  __syncthreads();   // single staging barrier: sA + sB + sRC all visible

  const int m16 = lane & 15, quad = lane >> 4;
  const int arow = 16 * wv + m16;

  // kv = feat @ [Wk|Wv]
  floatx4 acc[8];
#pragma unroll
  for (int i = 0; i < 8; ++i) acc[i] = (floatx4){0.f, 0.f, 0.f, 0.f};
#pragma unroll
  for (int ks = 0; ks < 3; ++ks) {
    short8 af = *(const short8*)&sA[arow][ks * 32 + quad * 8];
#pragma unroll
    for (int nt = 0; nt < 8; ++nt) {
      short8 bf = *(const short8*)&sB[nt * 16 + m16][ks * 32 + quad * 8];
      acc[nt] = __builtin_amdgcn_mfma_f32_16x16x32_bf16(af, bf, acc[nt], 0, 0, 0);
    }
  }
#pragma unroll
  for (int nt = 0; nt < 4; ++nt) {
    float bk = bkv[2 * (m16 + 16 * nt)];
    float bv = bkv[2 * (m16 + 16 * nt) + 1];
#pragma unroll
    for (int r = 0; r < 4; ++r) { acc[nt][r] += bk; acc[nt + 4][r] += bv; }
  }
  // alpha = q . k -> ex = exp(alpha)   (no max stabilizer: |alpha| << 88)
  float part[4] = {0.f, 0.f, 0.f, 0.f};
#pragma unroll
  for (int r = 0; r < 4; ++r) {
    unsigned nrow = sRC[16 * wv + quad * 4 + r] >> 16;
    uint2 qp = *(const uint2*)(qg2 + (size_t)nrow * 64 + m16 * 4);
    part[r] += blo(qp.x) * acc[0][r] + bhi(qp.x) * acc[1][r] +
               blo(qp.y) * acc[2][r] + bhi(qp.y) * acc[3][r];
  }
#pragma unroll
  for (int off = 1; off < 16; off <<= 1) {
#pragma unroll
    for (int r = 0; r < 4; ++r) part[r] += __shfl_xor(part[r], off);
  }
  float ex[4];
#pragma unroll
  for (int r = 0; r < 4; ++r) ex[r] = __expf(part[r]);
  if (m16 == 0) {
#pragma unroll
    for (int r = 0; r < 4; ++r)
      exg[base + 16 * wv + quad * 4 + r] = ex[r];
  }
  // v (bf16) -> sA rows (wave-private) for the W1 GEMM; keep fp32 v in acc[4..7]
#pragma unroll
  for (int nt = 0; nt < 4; ++nt)
#pragma unroll
    for (int r = 0; r < 4; ++r)
      sA[16 * wv + quad * 4 + r][m16 + 16 * nt] = bf16_of(acc[4 + nt][r]);
  // park coord_diff in sA cols 64..75 (dead after this wave's own A-reads)
#pragma unroll
  for (int it = 0; it < 4; ++it)
    if (m16 < 12) sA[16 * wv + it * 4 + quad][64 + m16] = bf16_of(cdp[it]);

  __syncthreads();   // all waves done reading sB (GEMM1)
  {                  // overlay W1^T into sB's space from prefetched regs
    unsigned short* sw = &sB[0][0];
    *(uint4*)&sw[(size_t)tid * 8] = w1a;
    if (tid < 192) *(uint4*)&sw[(size_t)(512 + tid) * 8] = w1b;
  }
  __syncthreads();   // sW1t visible

  // t = silu(v @ W1 + b1)
  floatx4 tacc[4];
#pragma unroll
  for (int i = 0; i < 4; ++i) tacc[i] = (floatx4){0.f, 0.f, 0.f, 0.f};
#pragma unroll
  for (int ks = 0; ks < 2; ++ks) {
    short8 af = *(const short8*)&sA[arow][ks * 32 + quad * 8];
#pragma unroll
    for (int nt = 0; nt < 4; ++nt) {
      short8 bf = *(const short8*)&sW1t[nt * 16 + m16][ks * 32 + quad * 8];
      tacc[nt] = __builtin_amdgcn_mfma_f32_16x16x32_bf16(af, bf, tacc[nt], 0, 0, 0);
    }
  }
#pragma unroll
  for (int nt = 0; nt < 4; ++nt) {
    float bb = b1[m16 + 16 * nt];
#pragma unroll
    for (int r = 0; r < 4; ++r) {
      float t = tacc[nt][r] + bb;
      tacc[nt][r] = t * __builtin_amdgcn_rcpf(1.f + __expf(-t));  // silu, rcp
    }
  }
  // cv = t @ W2 : local partials, then 16-lane REDUCE-SCATTER (15 shfl)
  float w0[16];   // j = r*4+c
#pragma unroll
  for (int r = 0; r < 4; ++r)
#pragma unroll
    for (int c = 0; c < 4; ++c) w0[r * 4 + c] = 0.f;
#pragma unroll
  for (int nt = 0; nt < 4; ++nt) {
    float4 w2r = ((const float4*)W2)[m16 + 16 * nt];
#pragma unroll
    for (int r = 0; r < 4; ++r) {
      w0[r * 4 + 0] += tacc[nt][r] * w2r.x;
      w0[r * 4 + 1] += tacc[nt][r] * w2r.y;
      w0[r * 4 + 2] += tacc[nt][r] * w2r.z;
      w0[r * 4 + 3] += tacc[nt][r] * w2r.w;
    }
  }
  float rs1[8];
#pragma unroll
  for (int jj = 0; jj < 8; ++jj) {
    float snd = (m16 & 8) ? w0[jj] : w0[jj + 8];
    float rcv = __shfl_xor(snd, 8);
    rs1[jj] = ((m16 & 8) ? w0[jj + 8] : w0[jj]) + rcv;
  }
  float rs2[4];
#pragma unroll
  for (int jj = 0; jj < 4; ++jj) {
    float snd = (m16 & 4) ? rs1[jj] : rs1[jj + 4];
    float rcv = __shfl_xor(snd, 4);
    rs2[jj] = ((m16 & 4) ? rs1[jj + 4] : rs1[jj]) + rcv;
  }
  float rs3[2];
#pragma unroll
  for (int jj = 0; jj < 2; ++jj) {
    float snd = (m16 & 2) ? rs2[jj] : rs2[jj + 2];
    float rcv = __shfl_xor(snd, 2);
    rs3[jj] = ((m16 & 2) ? rs2[jj + 2] : rs2[jj]) + rcv;
  }
  float cvtot;
  {
    float snd = (m16 & 1) ? rs3[0] : rs3[1];
    float rcv = __shfl_xor(snd, 1);
    cvtot = ((m16 & 1) ? rs3[1] : rs3[0]) + rcv;
  }
  // lane m16 holds cv[r=m16>>2][c=m16&3]; lane d wants channel d/3
  const int d3 = (m16 < 12) ? ((m16 * 11) >> 5) : 3;
  float tr[4];
#pragma unroll
  for (int r = 0; r < 4; ++r) {
    float cvv = __shfl(cvtot, (quad << 4) + r * 4 + d3);
    tr[r] = (m16 < 12) ? bf2f(sA[16 * wv + quad * 4 + r][64 + m16]) * cvv : 0.f;
  }

  // ---- per-wave segment reduce over this wave's 16 slots + atomics ----
  int s = 0;
  while (s < 16) {
    int n = (int)(sRC[16 * wv + s] >> 16);        // uniform (broadcast)
    int e2 = s + 1;
    while (e2 < 16 && (int)(sRC[16 * wv + e2] >> 16) == n) ++e2;
    float hp0 = 0.f, hp1 = 0.f, hp2 = 0.f, hp3 = 0.f, lp = 0.f, cp = 0.f;
#pragma unroll
    for (int r = 0; r < 4; ++r) {
      int rowi = quad * 4 + r;
      float w = (rowi >= s && rowi < e2) ? ex[r] : 0.f;
      hp0 += w * acc[4][r];
      hp1 += w * acc[5][r];
      hp2 += w * acc[6][r];
      hp3 += w * acc[7][r];
      lp  += (rowi >= s && rowi < e2) ? ex[r] : 0.f;
      cp  += w * tr[r];
    }
    hp0 += __shfl_xor(hp0, 16); hp0 += __shfl_xor(hp0, 32);
    hp1 += __shfl_xor(hp1, 16); hp1 += __shfl_xor(hp1, 32);
    hp2 += __shfl_xor(hp2, 16); hp2 += __shfl_xor(hp2, 32);
    hp3 += __shfl_xor(hp3, 16); hp3 += __shfl_xor(hp3, 32);
    lp  += __shfl_xor(lp, 16);  lp  += __shfl_xor(lp, 32);
    cp  += __shfl_xor(cp, 16);  cp  += __shfl_xor(cp, 32);
    if (quad == 0) {
      float* hg = hacc_g + (size_t)n * 64;
      atomicAdd(hg + m16,      hp0);
      atomicAdd(hg + m16 + 16, hp1);
      atomicAdd(hg + m16 + 32, hp2);
      atomicAdd(hg + m16 + 48, hp3);
      if (m16 < 12) atomicAdd(cacc_g + (size_t)n * 12 + m16, cp);
      if (m16 == 0) atomicAdd(l_g + n, lp);
    }
    s = e2;
  }
}

// ---------------- finalize (float4-granular: 16 threads/node) ----------------
__global__ __launch_bounds__(256)
void k_fin(const float* __restrict__ h, const float* __restrict__ coord,
           const int* __restrict__ row, const int* __restrict__ iperm,
           const float* __restrict__ exg, const float* __restrict__ l_g,
           const float* __restrict__ hacc_g, const float* __restrict__ cacc_g,
           float* __restrict__ out) {
  const int node = blockIdx.x * 16 + (threadIdx.x >> 4);
  const int q16 = threadIdx.x & 15;
  const float l = l_g[node];
  const float inv = (l > 0.f) ? 1.f / l : 0.f;
  {
    float4 hv = ((const float4*)(h + (size_t)node * 64))[q16];
    float4 av = ((const float4*)(hacc_g + (size_t)node * 64))[q16];
    float4 o;
    o.x = hv.x + av.x * inv; o.y = hv.y + av.y * inv;
    o.z = hv.z + av.z * inv; o.w = hv.w + av.w * inv;
    ((float4*)(out + (size_t)node * 64))[q16] = o;
  }
  if (q16 < 3) {
    float4 cv = ((const float4*)(coord + (size_t)node * 12))[q16];
    float4 av = ((const float4*)(cacc_g + (size_t)node * 12))[q16];
    float4 o;
    o.x = cv.x + av.x * inv; o.y = cv.y + av.y * inv;
    o.z = cv.z + av.z * inv; o.w = cv.w + av.w * inv;
    ((float4*)(out + (size_t)NN * 64 + (size_t)node * 12))[q16] = o;
  }
  const int e = blockIdx.x * 256 + threadIdx.x;   // covers [0, NE) exactly
  float le = l_g[row[e]];                          // node with an edge: le > 0
  out[(size_t)NN * 64 + NN * 12 + e] = exg[iperm[e]] * __builtin_amdgcn_rcpf(le);
}

extern "C" void kernel_launch(void* const* d_in, const int* in_sizes, int n_in,
                              void* d_out, int out_size, void* d_ws, size_t ws_size,
                              hipStream_t stream) {
  const float* h         = (const float*)d_in[0];
  const float* coord     = (const float*)d_in[1];
  const int*   row       = (const int*)d_in[2];
  const int*   col       = (const int*)d_in[3];
  const float* edge_attr = (const float*)d_in[4];
  const float* Wq        = (const float*)d_in[5];
  const float* bq        = (const float*)d_in[6];
  const float* Wkv       = (const float*)d_in[7];
  const float* bkv       = (const float*)d_in[8];
  const float* W1        = (const float*)d_in[9];
  const float* b1        = (const float*)d_in[10];
  const float* W2        = (const float*)d_in[11];
  float* out = (float*)d_out;

  size_t off = 0;
  char* wsb = (char*)d_ws;
  auto alloc = [&](size_t bytes) {
    off = (off + 255) & ~(size_t)255;
    void* p = wsb + off; off += bytes; return p;
  };
  // ---- zeroed region (contiguous, one memset) ----
  int*            deg      = (int*)alloc((size_t)NN * 4);
  float*          l_g      = (float*)alloc((size_t)NN * 4);
  float*          hacc_g   = (float*)alloc((size_t)NN * 64 * 4);
  float*          cacc_g   = (float*)alloc((size_t)NN * 12 * 4);
  size_t zbytes = off;
  // ---- rest ----
  float*          norm_part= (float*)alloc((size_t)NPREB * 16 * 4);
  float*          rnorm    = (float*)alloc(16 * 4);
  int*            cursor   = (int*)alloc((size_t)NN * 4);
  unsigned*       rcp      = (unsigned*)alloc((size_t)NE * 4);
  int*            iperm    = (int*)alloc((size_t)NE * 4);
  float*          exg      = (float*)alloc((size_t)NE * 4);
  uint4*          eab      = (uint4*)alloc((size_t)NE * 32);
  unsigned short* qg2      = (unsigned short*)alloc((size_t)NN * 64 * 2);
  unsigned short* hb       = (unsigned short*)alloc((size_t)NN * 64 * 2);
  unsigned short* Bkvb     = (unsigned short*)alloc(128 * 104 * 2);
  unsigned short* W1tb     = (unsigned short*)alloc(64 * 88 * 2);
  unsigned*       Wqp      = (unsigned*)alloc(32 * 64 * 4);

  hipMemsetAsync(d_ws, 0, zbytes, stream);

  k_pre<<<NPREB, 256, 0, stream>>>(coord, row, col, Wkv, W1, Wq,
                                   norm_part, deg, Bkvb, W1tb, Wqp);
  k_scanq<<<1 + NN / 16, 1024, 0, stream>>>(deg, cursor, norm_part,
                                            rnorm, h, Wqp, bq, qg2, hb);
  k_scatter<<<(NE + 255) / 256, 256, 0, stream>>>(row, col, edge_attr, cursor,
                                                  iperm, rcp, eab);
  k_kv<<<NE / 128, 512, 0, stream>>>(hb, coord, bkv, b1, W2, rnorm,
                                     rcp, eab, Bkvb, W1tb, qg2,
                                     exg, l_g, hacc_g, cacc_g);
  k_fin<<<NN / 16, 256, 0, stream>>>(h, coord, row, iperm, exg, l_g,
                                     hacc_g, cacc_g, out);
}

// Round 13
// 429.913 us; speedup vs baseline: 1.0760x; 1.0016x over previous
//
#include <hip/hip_runtime.h>
#include <math.h>

#define NN 50000
#define NE 800000
#define NPREB 1024   // k_pre grid (blocks); norm_part rows

typedef __attribute__((ext_vector_type(8))) short short8;
typedef __attribute__((ext_vector_type(4))) float floatx4;

__device__ __forceinline__ unsigned short bf16_of(float x) {
  unsigned u = __float_as_uint(x);
  u += 0x7fffu + ((u >> 16) & 1u);
  return (unsigned short)(u >> 16);
}
__device__ __forceinline__ float bf2f(unsigned short u) {
  return __uint_as_float(((unsigned)u) << 16);
}
__device__ __forceinline__ unsigned pack_bf(float a, float b) {
  unsigned ua = __float_as_uint(a); ua += 0x7fffu + ((ua >> 16) & 1u);
  unsigned ub = __float_as_uint(b); ub += 0x7fffu + ((ub >> 16) & 1u);
  return (ua >> 16) | (ub & 0xffff0000u);
}
__device__ __forceinline__ float blo(unsigned w) { return __uint_as_float(w << 16); }
__device__ __forceinline__ float bhi(unsigned w) { return __uint_as_float(w & 0xffff0000u); }

// ---------- k_pre: weight conversion + radial-norm partials + degree count ----------
__global__ __launch_bounds__(256)
void k_pre(const float* __restrict__ coord, const int* __restrict__ row,
           const int* __restrict__ col, const float* __restrict__ Wkv,
           const float* __restrict__ W1, const float* __restrict__ Wq,
           float* __restrict__ norm_part, int* __restrict__ deg,
           unsigned short* __restrict__ Bkvb, unsigned short* __restrict__ W1tb,
           unsigned short* __restrict__ Wqtb) {
  __shared__ float nred[4][16];
  const int gid = blockIdx.x * 256 + threadIdx.x;
  const int np = gridDim.x * 256;
  for (int idx = gid; idx < 128 * 96; idx += np) {
    int n = idx & 127, kk = idx >> 7;
    float w = (n < 64) ? Wkv[kk * 128 + 2 * n] : Wkv[kk * 128 + 2 * (n - 64) + 1];
    Bkvb[n * 104 + kk] = bf16_of(w);
  }
  for (int idx = gid; idx < 64 * 64; idx += np) {
    int n = idx & 63, kk = idx >> 6;
    W1tb[n * 88 + kk] = bf16_of(W1[kk * 64 + n]);
  }
  for (int idx = gid; idx < 64 * 64; idx += np) {
    int n = idx & 63, kk = idx >> 6;
    Wqtb[n * 64 + kk] = bf16_of(Wq[kk * 64 + n]);   // Wq^T bf16 (MFMA B-frag)
  }
  // ---- per-thread edge loop ----
  float accv[16];
#pragma unroll
  for (int j = 0; j < 16; ++j) accv[j] = 0.f;
  for (int e = gid; e < NE; e += np) {
    int r = row[e], c = col[e];
    const float4* cr = (const float4*)(coord + (size_t)r * 12);
    const float4* cc = (const float4*)(coord + (size_t)c * 12);
    float cd[12];
#pragma unroll
    for (int q = 0; q < 3; ++q) {
      float4 a = cr[q], b = cc[q];
      cd[q * 4 + 0] = a.x - b.x; cd[q * 4 + 1] = a.y - b.y;
      cd[q * 4 + 2] = a.z - b.z; cd[q * 4 + 3] = a.w - b.w;
    }
#pragma unroll
    for (int c4 = 0; c4 < 4; ++c4)
#pragma unroll
      for (int f4 = 0; f4 < 4; ++f4) {
        float v = cd[c4 * 3] * cd[f4 * 3] + cd[c4 * 3 + 1] * cd[f4 * 3 + 1] +
                  cd[c4 * 3 + 2] * cd[f4 * 3 + 2];
        accv[c4 * 4 + f4] += v * v;
      }
    atomicAdd(deg + r, 1);
  }
  // ---- one-time wave butterfly + block reduce ----
  const int lane = threadIdx.x & 63, wvb = threadIdx.x >> 6;
#pragma unroll
  for (int j = 0; j < 16; ++j) {
    accv[j] += __shfl_xor(accv[j], 1);
    accv[j] += __shfl_xor(accv[j], 2);
    accv[j] += __shfl_xor(accv[j], 4);
    accv[j] += __shfl_xor(accv[j], 8);
    accv[j] += __shfl_xor(accv[j], 16);
    accv[j] += __shfl_xor(accv[j], 32);
  }
  if (lane == 0) {
#pragma unroll
    for (int j = 0; j < 16; ++j) nred[wvb][j] = accv[j];   // static indices
  }
  __syncthreads();
  if (threadIdx.x < 16) {
    float s = nred[0][threadIdx.x] + nred[1][threadIdx.x] +
              nred[2][threadIdx.x] + nred[3][threadIdx.x];
    norm_part[blockIdx.x * 16 + threadIdx.x] = s;
  }
}

// ---------- k_scanq: block 0 = norm reduce + CSR scan; blocks >=1 = MFMA q ----
// q = h @ Wq as a real MFMA GEMM: one wave per 16 nodes (16 waves/block, 256
// nodes/block, 196 GEMM blocks vs 3125 GEMV blocks before). The bf16 convert
// feeds BOTH the LDS A-tile and the hb store. D-frag (col=lane&15,
// row=(lane>>4)*4+reg) packs directly into qg2's interleaved layout.
__global__ __launch_bounds__(1024)
void k_scanq(const int* __restrict__ deg, int* __restrict__ cursor,
             const float* __restrict__ norm_part, float* __restrict__ rnorm,
             const float* __restrict__ h, const unsigned short* __restrict__ Wqtb,
             const float* __restrict__ bq,
             unsigned short* __restrict__ qg2, unsigned short* __restrict__ hb) {
  __shared__ int part[1024];
  __shared__ float nr[64][16];
  __shared__ __align__(16) unsigned short sH[16][16][72];  // pad 72: bank spread
  const int t = threadIdx.x;
  if (blockIdx.x == 0) {
    {  // reduce norm_part[NPREB][16] -> rnorm[16], no atomics
      const int i = t >> 4, c = t & 15;
      float s = 0.f;
#pragma unroll
      for (int j = 0; j < NPREB / 64; ++j) s += norm_part[((i + 64 * j) << 4) + c];
      nr[i][c] = s;
    }
    __syncthreads();
    if (t < 16) {
      float s = 0.f;
#pragma unroll 8
      for (int i = 0; i < 64; ++i) s += nr[i][t];
      rnorm[t] = 1.0f / fmaxf(sqrtf(s), 1e-12f);
    }
    const int CH = (NN + 1023) / 1024;
    const int lo = t * CH, hi = (lo + CH < NN) ? lo + CH : NN;
    int s = 0;
    for (int i = lo; i < hi; ++i) s += deg[i];
    part[t] = s;
    __syncthreads();
    for (int off = 1; off < 1024; off <<= 1) {
      int v = (t >= off) ? part[t - off] : 0;
      __syncthreads();
      part[t] += v;
      __syncthreads();
    }
    int base = (t == 0) ? 0 : part[t - 1];
    for (int i = lo; i < hi; ++i) {
      cursor[i] = base; base += deg[i];
    }
    return;
  }
  const int wv = t >> 6, lane = t & 63;
  const int nbase = (blockIdx.x - 1) * 256 + wv * 16;
  if (nbase >= NN) return;                      // NN % 16 == 0: full waves only
  // 16 nodes x 64 feats: fp32 -> bf16 -> LDS A-tile + hb (coalesced)
  const float4* hsrc = (const float4*)(h + (size_t)nbase * 64);
#pragma unroll
  for (int i = 0; i < 4; ++i) {
    int fi = i * 64 + lane;           // float4 index in the 16x64 tile
    int nd = fi >> 4, c4 = fi & 15;   // node-in-tile, float4-column
    float4 v = hsrc[fi];
    uint2 u; u.x = pack_bf(v.x, v.y); u.y = pack_bf(v.z, v.w);
    *(uint2*)&sH[wv][nd][c4 * 4] = u;
    *(uint2*)&hb[((size_t)nbase + nd) * 64 + c4 * 4] = u;
  }
  const int m16 = lane & 15, quad = lane >> 4;
  floatx4 acc[4];
#pragma unroll
  for (int i = 0; i < 4; ++i) acc[i] = (floatx4){0.f, 0.f, 0.f, 0.f};
#pragma unroll
  for (int ks = 0; ks < 2; ++ks) {
    short8 af = *(const short8*)&sH[wv][m16][ks * 32 + quad * 8];
#pragma unroll
    for (int nt = 0; nt < 4; ++nt) {
      short8 bf = *(const short8*)&Wqtb[(nt * 16 + m16) * 64 + ks * 32 + quad * 8];
      acc[nt] = __builtin_amdgcn_mfma_f32_16x16x32_bf16(af, bf, acc[nt], 0, 0, 0);
    }
  }
  const float bq0 = bq[m16], bq1 = bq[16 + m16];
  const float bq2 = bq[32 + m16], bq3 = bq[48 + m16];
#pragma unroll
  for (int r = 0; r < 4; ++r) {
    size_t nd = (size_t)nbase + quad * 4 + r;
    uint2 u;
    u.x = pack_bf(acc[0][r] + bq0, acc[1][r] + bq1);   // feats m16, m16+16
    u.y = pack_bf(acc[2][r] + bq2, acc[3][r] + bq3);   // feats m16+32, m16+48
    *(uint2*)&qg2[nd * 64 + m16 * 4] = u;              // qg2 layout: m16*4 + nt
  }
}

// ---------- k_scatter: producer-side permute of edge data ----------
__global__ void k_scatter(const int* __restrict__ row, const int* __restrict__ col,
                          const float* __restrict__ edge_attr,
                          int* __restrict__ cursor, int* __restrict__ iperm,
                          unsigned* __restrict__ rcp, uint4* __restrict__ eab) {
  int e = blockIdx.x * 256 + threadIdx.x;
  if (e < NE) {
    int r = row[e], c = col[e];
    int p = atomicAdd(cursor + r, 1);
    iperm[e] = p;   // coalesced; lets k_fin write att coalesced
    rcp[p] = ((unsigned)r << 16) | (unsigned)c;
    const float4* ep = (const float4*)(edge_attr + (size_t)e * 16);
    float4 f0 = ep[0], f1 = ep[1], f2 = ep[2], f3 = ep[3];
    uint4 a, b;
    a.x = pack_bf(f0.x, f0.y); a.y = pack_bf(f0.z, f0.w);
    a.z = pack_bf(f1.x, f1.y); a.w = pack_bf(f1.z, f1.w);
    b.x = pack_bf(f2.x, f2.y); b.y = pack_bf(f2.z, f2.w);
    b.z = pack_bf(f3.x, f3.y); b.w = pack_bf(f3.z, f3.w);
    eab[(size_t)p * 2]     = a;
    eab[(size_t)p * 2 + 1] = b;
  }
}

// -------- main fused kernel (frozen — k_kv deltas < noise band) ------
__global__ __launch_bounds__(512, 6)
void k_kv(const unsigned short* __restrict__ hb, const float* __restrict__ coord,
          const float* __restrict__ bkv, const float* __restrict__ b1,
          const float* __restrict__ W2, const float* __restrict__ rnorm,
          const unsigned* __restrict__ rcp, const uint4* __restrict__ eab,
          const unsigned short* __restrict__ Bkvb,
          const unsigned short* __restrict__ W1tb,
          const unsigned short* __restrict__ qg2,
          float* __restrict__ exg, float* __restrict__ l_g,
          float* __restrict__ hacc_g, float* __restrict__ cacc_g) {
  __shared__ __align__(16) unsigned short sA[128][104];   // feat bf16; later v + cd
  __shared__ __align__(16) unsigned short sB[128][104];   // [k|v]^T bf16; later W1^T
  __shared__ unsigned sRC[128];                           // row<<16 | col
  unsigned short (*sW1t)[88] = (unsigned short (*)[88])&sB[0][0];

  const int tid = threadIdx.x;
  const int base = blockIdx.x * 128;

  // prefetch W1^T (11,264 B) into registers; parked into sB's space post-GEMM1
  const uint4* gw = (const uint4*)W1tb;
  uint4 w1a = gw[tid];                 // 704 uint4 total; tid<512 all valid
  uint4 w1b;
  if (tid < 192) w1b = gw[512 + tid];

  if (tid < 128) sRC[tid] = rcp[base + tid];        // for post-GEMM phases
  if (tid < 256) {                                  // edge_attr bf16, coalesced
    int s = tid >> 1;
    *(uint4*)&sA[s][80 + (tid & 1) * 8] = eab[(size_t)base * 2 + tid];
  }
  // hb gather starts immediately — col from rcp directly (8-way uniform)
  for (int idx = tid; idx < 1024; idx += 512) {
    int s = idx >> 3, k8 = idx & 7;
    unsigned c = rcp[base + s] & 0xffffu;
    uint4 u = ((const uint4*)(hb + (size_t)c * 64))[k8];
    *(uint4*)&sA[s][16 + k8 * 8] = u;
  }
  {
    const uint4* gb = (const uint4*)Bkvb;
    uint4* sb = (uint4*)&sB[0][0];
    for (int idx = tid; idx < 1664; idx += 512) sb[idx] = gb[idx];
  }
  const int wv = tid >> 6, lane = tid & 63;
  float cdp[4];   // this wave's coord_diff values, parked to LDS after GEMM1
  {
    const int grp = lane >> 4, g = lane & 15;
    const int c4 = g >> 2, f4 = g & 3;
    const float rn = rnorm[g];
#pragma unroll
    for (int it = 0; it < 4; ++it) {
      int slot = 16 * wv + it * 4 + grp;
      unsigned rc = rcp[base + slot];               // uniform per 16-lane group
      int r = (int)(rc >> 16), c = (int)(rc & 0xffffu);
      float cd = 0.f;
      if (g < 12) cd = coord[r * 12 + g] - coord[c * 12 + g];
      cdp[it] = cd;
      float rad = 0.f;
#pragma unroll
      for (int d = 0; d < 3; ++d)
        rad += __shfl(cd, grp * 16 + c4 * 3 + d) * __shfl(cd, grp * 16 + f4 * 3 + d);
      sA[slot][g] = bf16_of(rad * rn);
    }
  }
  __syncthreads();   // single staging barrier: sA + sB + sRC all visible

  const int m16 = lane & 15, quad = lane >> 4;
  const int arow = 16 * wv + m16;

  // kv = feat @ [Wk|Wv]
  floatx4 acc[8];
#pragma unroll
  for (int i = 0; i < 8; ++i) acc[i] = (floatx4){0.f, 0.f, 0.f, 0.f};
#pragma unroll
  for (int ks = 0; ks < 3; ++ks) {
    short8 af = *(const short8*)&sA[arow][ks * 32 + quad * 8];
#pragma unroll
    for (int nt = 0; nt < 8; ++nt) {
      short8 bf = *(const short8*)&sB[nt * 16 + m16][ks * 32 + quad * 8];
      acc[nt] = __builtin_amdgcn_mfma_f32_16x16x32_bf16(af, bf, acc[nt], 0, 0, 0);
    }
  }
#pragma unroll
  for (int nt = 0; nt < 4; ++nt) {
    float bk = bkv[2 * (m16 + 16 * nt)];
    float bv = bkv[2 * (m16 + 16 * nt) + 1];
#pragma unroll
    for (int r = 0; r < 4; ++r) { acc[nt][r] += bk; acc[nt + 4][r] += bv; }
  }
  // alpha = q . k -> ex = exp(alpha)   (no max stabilizer: |alpha| << 88)
  float part[4] = {0.f, 0.f, 0.f, 0.f};
#pragma unroll
  for (int r = 0; r < 4; ++r) {
    unsigned nrow = sRC[16 * wv + quad * 4 + r] >> 16;
    uint2 qp = *(const uint2*)(qg2 + (size_t)nrow * 64 + m16 * 4);
    part[r] += blo(qp.x) * acc[0][r] + bhi(qp.x) * acc[1][r] +
               blo(qp.y) * acc[2][r] + bhi(qp.y) * acc[3][r];
  }
#pragma unroll
  for (int off = 1; off < 16; off <<= 1) {
#pragma unroll
    for (int r = 0; r < 4; ++r) part[r] += __shfl_xor(part[r], off);
  }
  float ex[4];
#pragma unroll
  for (int r = 0; r < 4; ++r) ex[r] = __expf(part[r]);
  if (m16 == 0) {
#pragma unroll
    for (int r = 0; r < 4; ++r)
      exg[base + 16 * wv + quad * 4 + r] = ex[r];
  }
  // v (bf16) -> sA rows (wave-private) for the W1 GEMM; keep fp32 v in acc[4..7]
#pragma unroll
  for (int nt = 0; nt < 4; ++nt)
#pragma unroll
    for (int r = 0; r < 4; ++r)
      sA[16 * wv + quad * 4 + r][m16 + 16 * nt] = bf16_of(acc[4 + nt][r]);
  // park coord_diff in sA cols 64..75 (dead after this wave's own A-reads)
#pragma unroll
  for (int it = 0; it < 4; ++it)
    if (m16 < 12) sA[16 * wv + it * 4 + quad][64 + m16] = bf16_of(cdp[it]);

  __syncthreads();   // all waves done reading sB (GEMM1)
  {                  // overlay W1^T into sB's space from prefetched regs
    unsigned short* sw = &sB[0][0];
    *(uint4*)&sw[(size_t)tid * 8] = w1a;
    if (tid < 192) *(uint4*)&sw[(size_t)(512 + tid) * 8] = w1b;
  }
  __syncthreads();   // sW1t visible

  // t = silu(v @ W1 + b1)
  floatx4 tacc[4];
#pragma unroll
  for (int i = 0; i < 4; ++i) tacc[i] = (floatx4){0.f, 0.f, 0.f, 0.f};
#pragma unroll
  for (int ks = 0; ks < 2; ++ks) {
    short8 af = *(const short8*)&sA[arow][ks * 32 + quad * 8];
#pragma unroll
    for (int nt = 0; nt < 4; ++nt) {
      short8 bf = *(const short8*)&sW1t[nt * 16 + m16][ks * 32 + quad * 8];
      tacc[nt] = __builtin_amdgcn_mfma_f32_16x16x32_bf16(af, bf, tacc[nt], 0, 0, 0);
    }
  }
#pragma unroll
  for (int nt = 0; nt < 4; ++nt) {
    float bb = b1[m16 + 16 * nt];
#pragma unroll
    for (int r = 0; r < 4; ++r) {
      float t = tacc[nt][r] + bb;
      tacc[nt][r] = t * __builtin_amdgcn_rcpf(1.f + __expf(-t));  // silu, rcp
    }
  }
  // cv = t @ W2 : local partials, then 16-lane REDUCE-SCATTER (15 shfl)
  float w0[16];   // j = r*4+c
#pragma unroll
  for (int r = 0; r < 4; ++r)
#pragma unroll
    for (int c = 0; c < 4; ++c) w0[r * 4 + c] = 0.f;
#pragma unroll
  for (int nt = 0; nt < 4; ++nt) {
    float4 w2r = ((const float4*)W2)[m16 + 16 * nt];
#pragma unroll
    for (int r = 0; r < 4; ++r) {
      w0[r * 4 + 0] += tacc[nt][r] * w2r.x;
      w0[r * 4 + 1] += tacc[nt][r] * w2r.y;
      w0[r * 4 + 2] += tacc[nt][r] * w2r.z;
      w0[r * 4 + 3] += tacc[nt][r] * w2r.w;
    }
  }
  float rs1[8];
#pragma unroll
  for (int jj = 0; jj < 8; ++jj) {
    float snd = (m16 & 8) ? w0[jj] : w0[jj + 8];
    float rcv = __shfl_xor(snd, 8);
    rs1[jj] = ((m16 & 8) ? w0[jj + 8] : w0[jj]) + rcv;
  }
  float rs2[4];
#pragma unroll
  for (int jj = 0; jj < 4; ++jj) {
    float snd = (m16 & 4) ? rs1[jj] : rs1[jj + 4];
    float rcv = __shfl_xor(snd, 4);
    rs2[jj] = ((m16 & 4) ? rs1[jj + 4] : rs1[jj]) + rcv;
  }
  float rs3[2];
#pragma unroll
  for (int jj = 0; jj < 2; ++jj) {
    float snd = (m16 & 2) ? rs2[jj] : rs2[jj + 2];
    float rcv = __shfl_xor(snd, 2);
    rs3[jj] = ((m16 & 2) ? rs2[jj + 2] : rs2[jj]) + rcv;
  }
  float cvtot;
  {
    float snd = (m16 & 1) ? rs3[0] : rs3[1];
    float rcv = __shfl_xor(snd, 1);
    cvtot = ((m16 & 1) ? rs3[1] : rs3[0]) + rcv;
  }
  // lane m16 holds cv[r=m16>>2][c=m16&3]; lane d wants channel d/3
  const int d3 = (m16 < 12) ? ((m16 * 11) >> 5) : 3;
  float tr[4];
#pragma unroll
  for (int r = 0; r < 4; ++r) {
    float cvv = __shfl(cvtot, (quad << 4) + r * 4 + d3);
    tr[r] = (m16 < 12) ? bf2f(sA[16 * wv + quad * 4 + r][64 + m16]) * cvv : 0.f;
  }

  // ---- per-wave segment reduce over this wave's 16 slots + atomics ----
  int s = 0;
  while (s < 16) {
    int n = (int)(sRC[16 * wv + s] >> 16);        // uniform (broadcast)
    int e2 = s + 1;
    while (e2 < 16 && (int)(sRC[16 * wv + e2] >> 16) == n) ++e2;
    float hp0 = 0.f, hp1 = 0.f, hp2 = 0.f, hp3 = 0.f, lp = 0.f, cp = 0.f;
#pragma unroll
    for (int r = 0; r < 4; ++r) {
      int rowi = quad * 4 + r;
      float w = (rowi >= s && rowi < e2) ? ex[r] : 0.f;
      hp0 += w * acc[4][r];
      hp1 += w * acc[5][r];
      hp2 += w * acc[6][r];
      hp3 += w * acc[7][r];
      lp  += (rowi >= s && rowi < e2) ? ex[r] : 0.f;
      cp  += w * tr[r];
    }
    hp0 += __shfl_xor(hp0, 16); hp0 += __shfl_xor(hp0, 32);
    hp1 += __shfl_xor(hp1, 16); hp1 += __shfl_xor(hp1, 32);
    hp2 += __shfl_xor(hp2, 16); hp2 += __shfl_xor(hp2, 32);
    hp3 += __shfl_xor(hp3, 16); hp3 += __shfl_xor(hp3, 32);
    lp  += __shfl_xor(lp, 16);  lp  += __shfl_xor(lp, 32);
    cp  += __shfl_xor(cp, 16);  cp  += __shfl_xor(cp, 32);
    if (quad == 0) {
      float* hg = hacc_g + (size_t)n * 64;
      atomicAdd(hg + m16,      hp0);
      atomicAdd(hg + m16 + 16, hp1);
      atomicAdd(hg + m16 + 32, hp2);
      atomicAdd(hg + m16 + 48, hp3);
      if (m16 < 12) atomicAdd(cacc_g + (size_t)n * 12 + m16, cp);
      if (m16 == 0) atomicAdd(l_g + n, lp);
    }
    s = e2;
  }
}

// ---------------- finalize (float4-granular: 16 threads/node) ----------------
__global__ __launch_bounds__(256)
void k_fin(const float* __restrict__ h, const float* __restrict__ coord,
           const int* __restrict__ row, const int* __restrict__ iperm,
           const float* __restrict__ exg, const float* __restrict__ l_g,
           const float* __restrict__ hacc_g, const float* __restrict__ cacc_g,
           float* __restrict__ out) {
  const int node = blockIdx.x * 16 + (threadIdx.x >> 4);
  const int q16 = threadIdx.x & 15;
  const float l = l_g[node];
  const float inv = (l > 0.f) ? 1.f / l : 0.f;
  {
    float4 hv = ((const float4*)(h + (size_t)node * 64))[q16];
    float4 av = ((const float4*)(hacc_g + (size_t)node * 64))[q16];
    float4 o;
    o.x = hv.x + av.x * inv; o.y = hv.y + av.y * inv;
    o.z = hv.z + av.z * inv; o.w = hv.w + av.w * inv;
    ((float4*)(out + (size_t)node * 64))[q16] = o;
  }
  if (q16 < 3) {
    float4 cv = ((const float4*)(coord + (size_t)node * 12))[q16];
    float4 av = ((const float4*)(cacc_g + (size_t)node * 12))[q16];
    float4 o;
    o.x = cv.x + av.x * inv; o.y = cv.y + av.y * inv;
    o.z = cv.z + av.z * inv; o.w = cv.w + av.w * inv;
    ((float4*)(out + (size_t)NN * 64 + (size_t)node * 12))[q16] = o;
  }
  const int e = blockIdx.x * 256 + threadIdx.x;   // covers [0, NE) exactly
  float le = l_g[row[e]];                          // node with an edge: le > 0
  out[(size_t)NN * 64 + NN * 12 + e] = exg[iperm[e]] * __builtin_amdgcn_rcpf(le);
}

extern "C" void kernel_launch(void* const* d_in, const int* in_sizes, int n_in,
                              void* d_out, int out_size, void* d_ws, size_t ws_size,
                              hipStream_t stream) {
  const float* h         = (const float*)d_in[0];
  const float* coord     = (const float*)d_in[1];
  const int*   row       = (const int*)d_in[2];
  const int*   col       = (const int*)d_in[3];
  const float* edge_attr = (const float*)d_in[4];
  const float* Wq        = (const float*)d_in[5];
  const float* bq        = (const float*)d_in[6];
  const float* Wkv       = (const float*)d_in[7];
  const float* bkv       = (const float*)d_in[8];
  const float* W1        = (const float*)d_in[9];
  const float* b1        = (const float*)d_in[10];
  const float* W2        = (const float*)d_in[11];
  float* out = (float*)d_out;

  size_t off = 0;
  char* wsb = (char*)d_ws;
  auto alloc = [&](size_t bytes) {
    off = (off + 255) & ~(size_t)255;
    void* p = wsb + off; off += bytes; return p;
  };
  // ---- zeroed region (contiguous, one memset) ----
  int*            deg      = (int*)alloc((size_t)NN * 4);
  float*          l_g      = (float*)alloc((size_t)NN * 4);
  float*          hacc_g   = (float*)alloc((size_t)NN * 64 * 4);
  float*          cacc_g   = (float*)alloc((size_t)NN * 12 * 4);
  size_t zbytes = off;
  // ---- rest ----
  float*          norm_part= (float*)alloc((size_t)NPREB * 16 * 4);
  float*          rnorm    = (float*)alloc(16 * 4);
  int*            cursor   = (int*)alloc((size_t)NN * 4);
  unsigned*       rcp      = (unsigned*)alloc((size_t)NE * 4);
  int*            iperm    = (int*)alloc((size_t)NE * 4);
  float*          exg      = (float*)alloc((size_t)NE * 4);
  uint4*          eab      = (uint4*)alloc((size_t)NE * 32);
  unsigned short* qg2      = (unsigned short*)alloc((size_t)NN * 64 * 2);
  unsigned short* hb       = (unsigned short*)alloc((size_t)NN * 64 * 2);
  unsigned short* Bkvb     = (unsigned short*)alloc(128 * 104 * 2);
  unsigned short* W1tb     = (unsigned short*)alloc(64 * 88 * 2);
  unsigned short* Wqtb     = (unsigned short*)alloc(64 * 64 * 2);

  hipMemsetAsync(d_ws, 0, zbytes, stream);

  k_pre<<<NPREB, 256, 0, stream>>>(coord, row, col, Wkv, W1, Wq,
                                   norm_part, deg, Bkvb, W1tb, Wqtb);
  k_scanq<<<1 + (NN + 255) / 256, 1024, 0, stream>>>(deg, cursor, norm_part,
                                                     rnorm, h, Wqtb, bq, qg2, hb);
  k_scatter<<<(NE + 255) / 256, 256, 0, stream>>>(row, col, edge_attr, cursor,
                                                  iperm, rcp, eab);
  k_kv<<<NE / 128, 512, 0, stream>>>(hb, coord, bkv, b1, W2, rnorm,
                                     rcp, eab, Bkvb, W1tb, qg2,
                                     exg, l_g, hacc_g, cacc_g);
  k_fin<<<NN / 16, 256, 0, stream>>>(h, coord, row, iperm, exg, l_g,
                                     hacc_g, cacc_g, out);
}